// Round 4
// baseline (24482.890 us; speedup 1.0000x reference)
//
#include <hip/hip_runtime.h>
#include <math.h>

#define DD    1024
#define BB    128
#define G3    3072
#define VOUT  8000
#define S_SRC 256
#define S_TGT 128
#define SOS   1
#define GRID  768
#define KS_F  4      // fallback split-K

// ---------------------------------------------------------------------------
// Global barrier: monotonic counter, generation = old/GRID. Reset each launch
// by k_init (bar lives on its OWN cacheline, after tok[128] — round-3 bug was
// bar overlapping tok[64..]). Release: __syncthreads orders the block's
// writes, thread-0 agent fence + device-scope atomicAdd publishes. Acquire:
// fence after spin, then __syncthreads.
// ---------------------------------------------------------------------------
__device__ __forceinline__ void gbar(unsigned* bar) {
    __syncthreads();
    if (threadIdx.x == 0) {
        __threadfence();
        unsigned old = atomicAdd(bar, 1u);
        unsigned target = (old / GRID + 1u) * GRID;
        while (__hip_atomic_load(bar, __ATOMIC_RELAXED, __HIP_MEMORY_SCOPE_AGENT) < target)
            __builtin_amdgcn_s_sleep(1);
        __threadfence();
    }
    __syncthreads();
}

// ---------------------------------------------------------------------------
// init: h = 0, tok = SOS, barrier counter = 0  (no overlap: bar != tok range)
// ---------------------------------------------------------------------------
__global__ __launch_bounds__(256) void k_init(float* __restrict__ h, int* __restrict__ tok,
                                              unsigned* __restrict__ bar) {
    int idx = blockIdx.x * 256 + threadIdx.x;
    if (idx < BB * DD) h[idx] = 0.0f;
    if (idx < BB) tok[idx] = SOS;
    if (idx == 0) bar[0] = 0u;
}

// ---------------------------------------------------------------------------
// Shared GEMM core: BM=128, BN=32, BK=32 tile, 256 threads, 8x2 micro-tile.
// As stride 132 (rows 16B-aligned); Bs stride 34 (rows 8B-aligned).
// LDS total 21248 B -> 3 blocks/CU fits comfortably.
// ---------------------------------------------------------------------------
__device__ __forceinline__ void gemm_core(
    float (* __restrict__ As)[132], float (* __restrict__ Bs)[34],
    const float* __restrict__ A0, const float* __restrict__ A1,
    const float* __restrict__ A2, const float* __restrict__ A3,
    const float* __restrict__ Brow, int kbeg, int ntiles,
    float (&acc)[8][2])
{
    const int tid = threadIdx.x;
    const int kq  = (tid & 7) * 4;
    const int r0  = tid >> 3;
    const int tx  = tid & 15, ty = tid >> 4;
    const float* Arow[4] = {A0, A1, A2, A3};

    for (int t = 0; t < ntiles; ++t) {
        const int k0 = kbeg + t * 32;
        #pragma unroll
        for (int p = 0; p < 4; ++p) {
            float4 v = *reinterpret_cast<const float4*>(Arow[p] + k0 + kq);
            int m = r0 + p * 32;
            As[kq+0][m] = v.x; As[kq+1][m] = v.y; As[kq+2][m] = v.z; As[kq+3][m] = v.w;
        }
        {
            float4 v = *reinterpret_cast<const float4*>(Brow + k0 + kq);
            Bs[kq+0][r0] = v.x; Bs[kq+1][r0] = v.y; Bs[kq+2][r0] = v.z; Bs[kq+3][r0] = v.w;
        }
        __syncthreads();
        #pragma unroll
        for (int k = 0; k < 32; ++k) {
            float a[8];
            #pragma unroll
            for (int i = 0; i < 8; ++i) a[i] = As[k][ty*8 + i];
            float b0 = Bs[k][tx*2 + 0], b1 = Bs[k][tx*2 + 1];
            #pragma unroll
            for (int i = 0; i < 8; ++i) {
                acc[i][0] = fmaf(a[i], b0, acc[i][0]);
                acc[i][1] = fmaf(a[i], b1, acc[i][1]);
            }
        }
        __syncthreads();
    }
}

// ===========================================================================
// PERSISTENT PATH (grid = 768, 3 blocks/CU certified by host occupancy query)
// ===========================================================================

__global__ __launch_bounds__(256, 3) void k_enc_p(
    const float* __restrict__ emb, const int* __restrict__ src,
    const float* __restrict__ Wih, const float* __restrict__ bih,
    const float* __restrict__ Whh, const float* __restrict__ bhh,
    float* __restrict__ h, float* __restrict__ gh_p,
    float* __restrict__ gi_buf, int CH, unsigned* bar)
{
    __shared__ float As[32][132];
    __shared__ float Bs[32][34];
    const int bid = blockIdx.x, tid = threadIdx.x;
    const int r0 = tid >> 3, tx = tid & 15, ty = tid >> 4;

    for (int s = 0; s < S_SRC; ++s) {
        // ---- hoisted input projection for the next CH steps ----
        if ((s & (CH - 1)) == 0) {
            const int cs = bid / 96, nt = bid % 96;
            if (cs < CH) {                       // block-uniform
                const int* srow = src + (s + cs) * BB;
                const float* A0 = emb + (size_t)srow[r0 +  0] * DD;
                const float* A1 = emb + (size_t)srow[r0 + 32] * DD;
                const float* A2 = emb + (size_t)srow[r0 + 64] * DD;
                const float* A3 = emb + (size_t)srow[r0 + 96] * DD;
                float acc[8][2] = {};
                gemm_core(As, Bs, A0, A1, A2, A3,
                          Wih + (size_t)(nt*32 + r0) * DD, 0, DD/32, acc);
                float* C = gi_buf + (size_t)cs * (BB * G3);
                #pragma unroll
                for (int i = 0; i < 8; ++i) {
                    int m = ty*8 + i;
                    #pragma unroll
                    for (int j = 0; j < 2; ++j) {
                        int n = nt*32 + tx*2 + j;
                        C[(size_t)m * G3 + n] = acc[i][j] + bih[n];
                    }
                }
            }
            gbar(bar);
        }
        // ---- recurrent gh GEMM: kh = bid/96 (KS=8, K-slice 128) ----
        {
            const int kh = bid / 96, nt = bid % 96;
            const float* A0 = h + (size_t)(r0 +  0) * DD;
            const float* A1 = h + (size_t)(r0 + 32) * DD;
            const float* A2 = h + (size_t)(r0 + 64) * DD;
            const float* A3 = h + (size_t)(r0 + 96) * DD;
            float acc[8][2] = {};
            gemm_core(As, Bs, A0, A1, A2, A3,
                      Whh + (size_t)(nt*32 + r0) * DD, kh * 128, 4, acc);
            float* C = gh_p + (size_t)kh * (BB * G3);
            #pragma unroll
            for (int i = 0; i < 8; ++i) {
                int m = ty*8 + i;
                C[(size_t)m * G3 + nt*32 + tx*2 + 0] = acc[i][0];
                C[(size_t)m * G3 + nt*32 + tx*2 + 1] = acc[i][1];
            }
        }
        gbar(bar);
        // ---- GRU update ----
        {
            int idx = bid * 256 + tid;
            if (idx < BB * DD) {
                int b = idx >> 10, d = idx & 1023;
                size_t o = (size_t)b * G3 + d;
                const float* gib = gi_buf + (size_t)(s & (CH-1)) * (BB * G3);
                float ir = gib[o], iz = gib[o + DD], in_ = gib[o + 2*DD];
                float hr = bhh[d], hz = bhh[DD + d], hn = bhh[2*DD + d];
                #pragma unroll
                for (int p = 0; p < 8; ++p) {
                    const float* g = gh_p + (size_t)p * (BB * G3);
                    hr += g[o]; hz += g[o + DD]; hn += g[o + 2*DD];
                }
                float r = 1.0f / (1.0f + expf(-(ir + hr)));
                float z = 1.0f / (1.0f + expf(-(iz + hz)));
                float n = tanhf(in_ + r * hn);
                h[idx] = (1.0f - z) * n + z * h[idx];
            }
        }
        gbar(bar);
    }
}

__global__ __launch_bounds__(256, 3) void k_dec_p(
    const float* __restrict__ emb,
    const float* __restrict__ Wih, const float* __restrict__ bih,
    const float* __restrict__ Whh, const float* __restrict__ bhh,
    const float* __restrict__ outW, const float* __restrict__ outb,
    float* __restrict__ h, float* __restrict__ g_p,
    float* __restrict__ lg_p, int* __restrict__ tok,
    float* __restrict__ out, int KSL, unsigned* bar)
{
    __shared__ float As[32][132];
    __shared__ float Bs[32][34];
    float* sv = &As[0][0];            // overlap: argmax phase never uses As/Bs
    int*   si = (int*)&As[8][0];
    const int bid = blockIdx.x, tid = threadIdx.x;
    const int r0 = tid >> 3, tx = tid & 15, ty = tid >> 4;

    for (int t = 0; t < S_TGT; ++t) {
        // ---- gates: side=bid/384, kh=(bid%384)/96, nt=bid%96 (KS=4) ----
        {
            const int side = bid / 384;
            const int rem  = bid - side * 384;
            const int kh   = rem / 96, nt = rem % 96;
            const float *A0, *A1, *A2, *A3;
            if (side) {
                A0 = h + (size_t)(r0 +  0) * DD;
                A1 = h + (size_t)(r0 + 32) * DD;
                A2 = h + (size_t)(r0 + 64) * DD;
                A3 = h + (size_t)(r0 + 96) * DD;
            } else {
                A0 = emb + (size_t)tok[r0 +  0] * DD;
                A1 = emb + (size_t)tok[r0 + 32] * DD;
                A2 = emb + (size_t)tok[r0 + 64] * DD;
                A3 = emb + (size_t)tok[r0 + 96] * DD;
            }
            const float* W = side ? Whh : Wih;
            float acc[8][2] = {};
            gemm_core(As, Bs, A0, A1, A2, A3,
                      W + (size_t)(nt*32 + r0) * DD, kh * 256, 8, acc);
            float* C = g_p + (size_t)(side*4 + kh) * (BB * G3);
            #pragma unroll
            for (int i = 0; i < 8; ++i) {
                int m = ty*8 + i;
                C[(size_t)m * G3 + nt*32 + tx*2 + 0] = acc[i][0];
                C[(size_t)m * G3 + nt*32 + tx*2 + 1] = acc[i][1];
            }
        }
        gbar(bar);
        // ---- GRU update: gi = slots 0..3 + bih, gh = slots 4..7 + bhh ----
        {
            int idx = bid * 256 + tid;
            if (idx < BB * DD) {
                int b = idx >> 10, d = idx & 1023;
                size_t o = (size_t)b * G3 + d;
                float ir = bih[d], iz = bih[DD + d], in_ = bih[2*DD + d];
                #pragma unroll
                for (int p = 0; p < 4; ++p) {
                    const float* g = g_p + (size_t)p * (BB * G3);
                    ir += g[o]; iz += g[o + DD]; in_ += g[o + 2*DD];
                }
                float hr = bhh[d], hz = bhh[DD + d], hn = bhh[2*DD + d];
                #pragma unroll
                for (int p = 4; p < 8; ++p) {
                    const float* g = g_p + (size_t)p * (BB * G3);
                    hr += g[o]; hz += g[o + DD]; hn += g[o + 2*DD];
                }
                float r = 1.0f / (1.0f + expf(-(ir + hr)));
                float z = 1.0f / (1.0f + expf(-(iz + hz)));
                float n = tanhf(in_ + r * hn);
                h[idx] = (1.0f - z) * n + z * h[idx];
            }
        }
        gbar(bar);
        // ---- logits: kh=bid/250 (<KSL active), nt=bid%250 ----
        {
            const int kh = bid / 250, nt = bid % 250;
            if (kh < KSL) {                      // block-uniform
                const int t0 = (32 * kh) / KSL, t1 = (32 * (kh + 1)) / KSL;
                const float* A0 = h + (size_t)(r0 +  0) * DD;
                const float* A1 = h + (size_t)(r0 + 32) * DD;
                const float* A2 = h + (size_t)(r0 + 64) * DD;
                const float* A3 = h + (size_t)(r0 + 96) * DD;
                float acc[8][2] = {};
                gemm_core(As, Bs, A0, A1, A2, A3,
                          outW + (size_t)(nt*32 + r0) * DD, t0 * 32, t1 - t0, acc);
                float* C = lg_p + (size_t)kh * (BB * VOUT);
                #pragma unroll
                for (int i = 0; i < 8; ++i) {
                    int m = ty*8 + i;
                    C[(size_t)m * VOUT + nt*32 + tx*2 + 0] = acc[i][0];
                    C[(size_t)m * VOUT + nt*32 + tx*2 + 1] = acc[i][1];
                }
            }
        }
        gbar(bar);
        // ---- fused: sum partials + bias -> out row, argmax -> tok ----
        if (bid < BB) {                          // block-uniform
            const int b = bid;
            const size_t ro = (size_t)b * VOUT;
            float* Ct = out + (size_t)t * (BB * VOUT) + ro;
            float bv = -INFINITY; int bi = 0x7fffffff;
            for (int v = tid * 4; v < VOUT; v += 1024) {
                float4 rr = *reinterpret_cast<const float4*>(outb + v);
                for (int kh = 0; kh < KSL; ++kh) {
                    float4 p = *reinterpret_cast<const float4*>(
                        lg_p + (size_t)kh * (BB * VOUT) + ro + v);
                    rr.x += p.x; rr.y += p.y; rr.z += p.z; rr.w += p.w;
                }
                *reinterpret_cast<float4*>(Ct + v) = rr;
                if (rr.x > bv) { bv = rr.x; bi = v + 0; }
                if (rr.y > bv) { bv = rr.y; bi = v + 1; }
                if (rr.z > bv) { bv = rr.z; bi = v + 2; }
                if (rr.w > bv) { bv = rr.w; bi = v + 3; }
            }
            sv[tid] = bv; si[tid] = bi;
            __syncthreads();
            for (int st = 128; st > 0; st >>= 1) {
                if (tid < st) {
                    if (sv[tid+st] > sv[tid] ||
                        (sv[tid+st] == sv[tid] && si[tid+st] < si[tid])) {
                        sv[tid] = sv[tid+st]; si[tid] = si[tid+st];
                    }
                }
                __syncthreads();
            }
            if (tid == 0) tok[b] = si[0];
        }
        gbar(bar);
    }
}

// ===========================================================================
// FALLBACK PATH (round-1 proven multi-launch kernels)
// ===========================================================================

__global__ __launch_bounds__(256) void k_gi_chunk(
    const float* __restrict__ emb, const int* __restrict__ src_c,
    const float* __restrict__ Wih, const float* __restrict__ bih,
    float* __restrict__ gi_buf)
{
    __shared__ float As[32][132];
    __shared__ float Bs[32][34];
    const int n0    = blockIdx.x * 32;
    const int mbase = blockIdx.y * 128;
    const int tid = threadIdx.x;
    const int r0  = tid >> 3, tx = tid & 15, ty = tid >> 4;

    const float* A[4];
    #pragma unroll
    for (int p = 0; p < 4; ++p)
        A[p] = emb + (size_t)src_c[mbase + r0 + p * 32] * DD;
    float acc[8][2] = {};
    gemm_core(As, Bs, A[0], A[1], A[2], A[3],
              Wih + (size_t)(n0 + r0) * DD, 0, DD/32, acc);
    #pragma unroll
    for (int i = 0; i < 8; ++i) {
        size_t m = (size_t)(mbase + ty*8 + i);
        #pragma unroll
        for (int j = 0; j < 2; ++j) {
            int n = n0 + tx*2 + j;
            gi_buf[m * G3 + n] = acc[i][j] + bih[n];
        }
    }
}

__global__ __launch_bounds__(256) void k_gates_ks(
    const float* __restrict__ emb, const int* __restrict__ tok,
    const float* __restrict__ h,
    const float* __restrict__ Wih, const float* __restrict__ Whh,
    float* __restrict__ gi_base, float* __restrict__ gh_base,
    int side_base)
{
    __shared__ float As[32][132];
    __shared__ float Bs[32][34];
    const int side = side_base + blockIdx.y;
    const int kh   = blockIdx.z;
    const int kseg = DD / KS_F;
    const float* __restrict__ W = side ? Whh : Wih;
    float* __restrict__ C = (side ? gh_base : gi_base) + (size_t)kh * (BB * G3);

    const int n0  = blockIdx.x * 32;
    const int tid = threadIdx.x;
    const int r0  = tid >> 3, tx = tid & 15, ty = tid >> 4;

    const float* A[4];
    #pragma unroll
    for (int p = 0; p < 4; ++p) {
        int m = r0 + p * 32;
        A[p] = side ? (h + (size_t)m * DD) : (emb + (size_t)tok[m] * DD);
    }
    float acc[8][2] = {};
    gemm_core(As, Bs, A[0], A[1], A[2], A[3],
              W + (size_t)(n0 + r0) * DD, kh * kseg, kseg / 32, acc);
    #pragma unroll
    for (int i = 0; i < 8; ++i) {
        size_t m = (size_t)(ty*8 + i);
        C[m * G3 + n0 + tx*2 + 0] = acc[i][0];
        C[m * G3 + n0 + tx*2 + 1] = acc[i][1];
    }
}

__global__ __launch_bounds__(256) void k_logits_ks(
    const float* __restrict__ h, const float* __restrict__ W,
    float* __restrict__ p_base)
{
    __shared__ float As[32][132];
    __shared__ float Bs[32][34];
    const int kh   = blockIdx.y;          // KSL fixed = 2
    const int kseg = DD / 2;
    float* __restrict__ C = p_base + (size_t)kh * (BB * VOUT);

    const int n0  = blockIdx.x * 32;
    const int tid = threadIdx.x;
    const int r0  = tid >> 3, tx = tid & 15, ty = tid >> 4;

    const float* A[4];
    #pragma unroll
    for (int p = 0; p < 4; ++p) A[p] = h + (size_t)(r0 + p * 32) * DD;
    float acc[8][2] = {};
    gemm_core(As, Bs, A[0], A[1], A[2], A[3],
              W + (size_t)(n0 + r0) * DD, kh * kseg, kseg / 32, acc);
    #pragma unroll
    for (int i = 0; i < 8; ++i) {
        size_t m = (size_t)(ty*8 + i);
        C[m * VOUT + n0 + tx*2 + 0] = acc[i][0];
        C[m * VOUT + n0 + tx*2 + 1] = acc[i][1];
    }
}

__global__ __launch_bounds__(256) void k_update_f(
    const float* __restrict__ gi_base, int ns_i, const float* __restrict__ bih,
    const float* __restrict__ gh_base, int ns_h, const float* __restrict__ bhh,
    float* __restrict__ h)
{
    int idx = blockIdx.x * 256 + threadIdx.x;
    int b = idx >> 10, d = idx & 1023;
    size_t o = (size_t)b * G3 + d;

    float ir = 0.f, iz = 0.f, in_ = 0.f;
    for (int p = 0; p < ns_i; ++p) {
        const float* g = gi_base + (size_t)p * (BB * G3);
        ir += g[o]; iz += g[o + DD]; in_ += g[o + 2*DD];
    }
    if (bih) { ir += bih[d]; iz += bih[DD + d]; in_ += bih[2*DD + d]; }

    float hr = 0.f, hz = 0.f, hn = 0.f;
    for (int p = 0; p < ns_h; ++p) {
        const float* g = gh_base + (size_t)p * (BB * G3);
        hr += g[o]; hz += g[o + DD]; hn += g[o + 2*DD];
    }
    hr += bhh[d]; hz += bhh[DD + d]; hn += bhh[2*DD + d];

    float r = 1.0f / (1.0f + expf(-(ir + hr)));
    float z = 1.0f / (1.0f + expf(-(iz + hz)));
    float n = tanhf(in_ + r * hn);
    float hv = h[idx];
    h[idx] = (1.0f - z) * n + z * hv;
}

__global__ __launch_bounds__(256) void k_argmax_out(
    const float* __restrict__ p0, const float* __restrict__ p1,
    const float* __restrict__ bias,
    float* __restrict__ outC, int* __restrict__ tok)
{
    const int b = blockIdx.x;
    const size_t ro = (size_t)b * VOUT;
    const int tid = threadIdx.x;

    float bv = -INFINITY; int bi = 0x7fffffff;
    for (int v = tid * 4; v < VOUT; v += 1024) {
        float4 a = *reinterpret_cast<const float4*>(p0 + ro + v);
        float4 c = *reinterpret_cast<const float4*>(p1 + ro + v);
        float4 bb = *reinterpret_cast<const float4*>(bias + v);
        float4 r;
        r.x = a.x + c.x + bb.x;
        r.y = a.y + c.y + bb.y;
        r.z = a.z + c.z + bb.z;
        r.w = a.w + c.w + bb.w;
        *reinterpret_cast<float4*>(outC + ro + v) = r;
        if (r.x > bv) { bv = r.x; bi = v + 0; }
        if (r.y > bv) { bv = r.y; bi = v + 1; }
        if (r.z > bv) { bv = r.z; bi = v + 2; }
        if (r.w > bv) { bv = r.w; bi = v + 3; }
    }
    __shared__ float sv[256];
    __shared__ int   si[256];
    sv[tid] = bv; si[tid] = bi;
    __syncthreads();
    for (int s = 128; s > 0; s >>= 1) {
        if (tid < s) {
            if (sv[tid+s] > sv[tid] || (sv[tid+s] == sv[tid] && si[tid+s] < si[tid])) {
                sv[tid] = sv[tid+s]; si[tid] = si[tid+s];
            }
        }
        __syncthreads();
    }
    if (tid == 0) tok[b] = si[0];
}

// ---------------------------------------------------------------------------
extern "C" void kernel_launch(void* const* d_in, const int* in_sizes, int n_in,
                              void* d_out, int out_size, void* d_ws, size_t ws_size,
                              hipStream_t stream) {
    const int*   src     = (const int*)  d_in[0];
    const float* enc_emb = (const float*)d_in[2];
    const float* eWih    = (const float*)d_in[3];
    const float* eWhh    = (const float*)d_in[4];
    const float* ebih    = (const float*)d_in[5];
    const float* ebhh    = (const float*)d_in[6];
    const float* dec_emb = (const float*)d_in[7];
    const float* dWih    = (const float*)d_in[8];
    const float* dWhh    = (const float*)d_in[9];
    const float* dbih    = (const float*)d_in[10];
    const float* dbhh    = (const float*)d_in[11];
    const float* outW    = (const float*)d_in[12];
    const float* outb    = (const float*)d_in[13];
    float* out = (float*)d_out;

    // workspace layout (bar strictly AFTER tok[0..127] — round-3 fix)
    float* h    = (float*)d_ws;                 // 128*1024
    float* g_p  = h + BB * DD;                  // 8 * 128*3072 (gate partials)
    int*  tok   = (int*)(g_p + 8 * BB * G3);    // tok[0..127]
    unsigned* bar = (unsigned*)(tok + 128);     // own 128B line
    float* scratch = (float*)(tok + 256);       // enc gi chunks / logits partials

    size_t fixed = (size_t)((char*)scratch - (char*)d_ws);
    size_t avail = (ws_size > fixed) ? ws_size - fixed : 0;
    int KSLv = (avail >= (size_t)3 * BB * VOUT * 4) ? 3 : 2;
    int CH = 8;
    while (CH > 1 && (size_t)CH * BB * G3 * 4 > avail) CH >>= 1;

    float* gi_buf = scratch;                    // encoder phase
    float* lg_p   = scratch;                    // decoder phase

    // certify persistent-path co-residency (host-only queries, capture-safe)
    static int persist_ok = -1;
    if (persist_ok < 0) {
        int nb_e = 0, nb_d = 0, ncu = 0, dev = 0;
        hipError_t e0 = hipGetDevice(&dev);
        hipError_t e1 = hipOccupancyMaxActiveBlocksPerMultiprocessor(
            &nb_e, (const void*)k_enc_p, 256, 0);
        hipError_t e2 = hipOccupancyMaxActiveBlocksPerMultiprocessor(
            &nb_d, (const void*)k_dec_p, 256, 0);
        hipError_t e3 = hipDeviceGetAttribute(
            &ncu, hipDeviceAttributeMultiprocessorCount, dev);
        persist_ok = (e0 == hipSuccess && e1 == hipSuccess && e2 == hipSuccess &&
                      e3 == hipSuccess && nb_e >= 3 && nb_d >= 3 &&
                      (long)ncu * 3 >= GRID) ? 1 : 0;
    }

    k_init<<<512, 256, 0, stream>>>(h, tok, bar);

    if (persist_ok == 1) {
        k_enc_p<<<GRID, 256, 0, stream>>>(enc_emb, src, eWih, ebih, eWhh, ebhh,
                                          h, g_p, gi_buf, CH, bar);
        k_dec_p<<<GRID, 256, 0, stream>>>(dec_emb, dWih, dbih, dWhh, dbhh,
                                          outW, outb, h, g_p, lg_p, tok,
                                          out, KSLv, bar);
    } else {
        // ---- round-1 proven multi-launch path ----
        float* gi_p = g_p;                      // slots 0..3
        float* gh_p = g_p + 4 * BB * G3;        // slots 4..7
        float* p0   = scratch;
        float* p1   = scratch + BB * VOUT;

        for (int c = 0; c < S_SRC; c += CH) {
            k_gi_chunk<<<dim3(96, CH), 256, 0, stream>>>(enc_emb, src + c * BB,
                                                         eWih, ebih, gi_buf);
            for (int s = 0; s < CH; ++s) {
                k_gates_ks<<<dim3(96, 1, KS_F), 256, 0, stream>>>(
                    enc_emb, tok, h, eWih, eWhh, nullptr, gh_p, 1);
                k_update_f<<<512, 256, 0, stream>>>(
                    gi_buf + (size_t)s * BB * G3, 1, nullptr, gh_p, KS_F, ebhh, h);
            }
        }
        for (int t = 0; t < S_TGT; ++t) {
            k_gates_ks<<<dim3(96, 2, KS_F), 256, 0, stream>>>(
                dec_emb, tok, h, dWih, dWhh, gi_p, gh_p, 0);
            k_update_f<<<512, 256, 0, stream>>>(gi_p, KS_F, dbih, gh_p, KS_F, dbhh, h);
            k_logits_ks<<<dim3(250, 2), 256, 0, stream>>>(h, outW, p0);
            float* Ct = out + (size_t)t * BB * VOUT;
            k_argmax_out<<<128, 256, 0, stream>>>(p0, p1, outb, Ct, tok);
        }
    }
}

// Round 5
// 24475.320 us; speedup vs baseline: 1.0003x; 1.0003x over previous
//
#include <hip/hip_runtime.h>
#include <math.h>

#define DD    1024
#define BB    128
#define G3    3072
#define VOUT  8000
#define S_SRC 256
#define S_TGT 128
#define SOS   1
#define GRID  768
#define KS_F  4      // fallback split-K

// ---------------------------------------------------------------------------
// Agent-scope (device-coherent, sc1) accessors. These bypass the per-XCD L2
// and are served by the shared Infinity Cache, so cross-XCD visibility needs
// only vmcnt-drain — NO buffer_wbl2/buffer_inv (the round-4 killer).
// Invariant: any array touched by these is NEVER touched by cached ops
// inside the persistent kernels.
// ---------------------------------------------------------------------------
__device__ __forceinline__ float cload(const float* p) {
    return __hip_atomic_load(p, __ATOMIC_RELAXED, __HIP_MEMORY_SCOPE_AGENT);
}
__device__ __forceinline__ void cstore(float* p, float v) {
    __hip_atomic_store(p, v, __ATOMIC_RELAXED, __HIP_MEMORY_SCOPE_AGENT);
}
__device__ __forceinline__ int cloadi(const int* p) {
    return __hip_atomic_load(p, __ATOMIC_RELAXED, __HIP_MEMORY_SCOPE_AGENT);
}
__device__ __forceinline__ void cstorei(int* p, int v) {
    __hip_atomic_store(p, v, __ATOMIC_RELAXED, __HIP_MEMORY_SCOPE_AGENT);
}

// ---------------------------------------------------------------------------
// Global barrier (lean): all cross-block data is sc1 (at L3 once vmcnt
// drains), so release = s_waitcnt only. __syncthreads already drains vmcnt
// per wave before s_barrier; the explicit s_waitcnt(0) is belt-and-braces.
// ---------------------------------------------------------------------------
__device__ __forceinline__ void gbar(unsigned* bar) {
    __builtin_amdgcn_s_waitcnt(0);
    __syncthreads();
    if (threadIdx.x == 0) {
        unsigned old = __hip_atomic_fetch_add(bar, 1u, __ATOMIC_RELAXED,
                                              __HIP_MEMORY_SCOPE_AGENT);
        unsigned target = (old / GRID + 1u) * GRID;
        while (__hip_atomic_load(bar, __ATOMIC_RELAXED,
                                 __HIP_MEMORY_SCOPE_AGENT) < target)
            __builtin_amdgcn_s_sleep(1);
    }
    __syncthreads();
}

// ---------------------------------------------------------------------------
// init: h = 0, tok = SOS, barrier counter = 0 (bar on its own line after tok)
// ---------------------------------------------------------------------------
__global__ __launch_bounds__(256) void k_init(float* __restrict__ h, int* __restrict__ tok,
                                              unsigned* __restrict__ bar) {
    int idx = blockIdx.x * 256 + threadIdx.x;
    if (idx < BB * DD) h[idx] = 0.0f;
    if (idx < BB) tok[idx] = SOS;
    if (idx == 0) bar[0] = 0u;
}

// ---------------------------------------------------------------------------
// Shared GEMM core: BM=128, BN=32, BK=32 tile, 256 threads, 8x2 micro-tile.
// COHA: A rows are cross-block data (h) -> agent-scope scalar loads.
// B rows (weights) always use normal cached float4 loads (L2-resident).
// ---------------------------------------------------------------------------
template<bool COHA>
__device__ __forceinline__ void gemm_core(
    float (* __restrict__ As)[132], float (* __restrict__ Bs)[34],
    const float* __restrict__ A0, const float* __restrict__ A1,
    const float* __restrict__ A2, const float* __restrict__ A3,
    const float* __restrict__ Brow, int kbeg, int ntiles,
    float (&acc)[8][2])
{
    const int tid = threadIdx.x;
    const int kq  = (tid & 7) * 4;
    const int r0  = tid >> 3;
    const int tx  = tid & 15, ty = tid >> 4;
    const float* Arow[4] = {A0, A1, A2, A3};

    for (int t = 0; t < ntiles; ++t) {
        const int k0 = kbeg + t * 32;
        #pragma unroll
        for (int p = 0; p < 4; ++p) {
            const float* ap = Arow[p] + k0 + kq;
            float vx, vy, vz, vw;
            if (COHA) {
                vx = cload(ap + 0); vy = cload(ap + 1);
                vz = cload(ap + 2); vw = cload(ap + 3);
            } else {
                float4 v = *reinterpret_cast<const float4*>(ap);
                vx = v.x; vy = v.y; vz = v.z; vw = v.w;
            }
            int m = r0 + p * 32;
            As[kq+0][m] = vx; As[kq+1][m] = vy; As[kq+2][m] = vz; As[kq+3][m] = vw;
        }
        {
            float4 v = *reinterpret_cast<const float4*>(Brow + k0 + kq);
            Bs[kq+0][r0] = v.x; Bs[kq+1][r0] = v.y; Bs[kq+2][r0] = v.z; Bs[kq+3][r0] = v.w;
        }
        __syncthreads();
        #pragma unroll
        for (int k = 0; k < 32; ++k) {
            float a[8];
            #pragma unroll
            for (int i = 0; i < 8; ++i) a[i] = As[k][ty*8 + i];
            float b0 = Bs[k][tx*2 + 0], b1 = Bs[k][tx*2 + 1];
            #pragma unroll
            for (int i = 0; i < 8; ++i) {
                acc[i][0] = fmaf(a[i], b0, acc[i][0]);
                acc[i][1] = fmaf(a[i], b1, acc[i][1]);
            }
        }
        __syncthreads();
    }
}

// ===========================================================================
// PERSISTENT PATH (grid = 768, 3 blocks/CU certified by host occupancy query)
// ===========================================================================

__global__ __launch_bounds__(256, 3) void k_enc_p(
    const float* __restrict__ emb, const int* __restrict__ src,
    const float* __restrict__ Wih, const float* __restrict__ bih,
    const float* __restrict__ Whh, const float* __restrict__ bhh,
    float* __restrict__ h, float* __restrict__ gh_p,
    float* __restrict__ gi_buf, int CH, unsigned* bar)
{
    __shared__ float As[32][132];
    __shared__ float Bs[32][34];
    const int bid = blockIdx.x, tid = threadIdx.x;
    const int r0 = tid >> 3, tx = tid & 15, ty = tid >> 4;

    for (int s = 0; s < S_SRC; ++s) {
        // ---- hoisted input projection for the next CH steps (cached A) ----
        if ((s & (CH - 1)) == 0) {
            const int cs = bid / 96, nt = bid % 96;
            if (cs < CH) {                       // block-uniform
                const int* srow = src + (s + cs) * BB;
                const float* A0 = emb + (size_t)srow[r0 +  0] * DD;
                const float* A1 = emb + (size_t)srow[r0 + 32] * DD;
                const float* A2 = emb + (size_t)srow[r0 + 64] * DD;
                const float* A3 = emb + (size_t)srow[r0 + 96] * DD;
                float acc[8][2] = {};
                gemm_core<false>(As, Bs, A0, A1, A2, A3,
                                 Wih + (size_t)(nt*32 + r0) * DD, 0, DD/32, acc);
                float* C = gi_buf + (size_t)cs * (BB * G3);
                #pragma unroll
                for (int i = 0; i < 8; ++i) {
                    int m = ty*8 + i;
                    #pragma unroll
                    for (int j = 0; j < 2; ++j) {
                        int n = nt*32 + tx*2 + j;
                        cstore(&C[(size_t)m * G3 + n], acc[i][j] + bih[n]);
                    }
                }
            }
            gbar(bar);
        }
        // ---- recurrent gh GEMM: kh = bid/96 (KS=8, K-slice 128), coh A ----
        {
            const int kh = bid / 96, nt = bid % 96;
            const float* A0 = h + (size_t)(r0 +  0) * DD;
            const float* A1 = h + (size_t)(r0 + 32) * DD;
            const float* A2 = h + (size_t)(r0 + 64) * DD;
            const float* A3 = h + (size_t)(r0 + 96) * DD;
            float acc[8][2] = {};
            gemm_core<true>(As, Bs, A0, A1, A2, A3,
                            Whh + (size_t)(nt*32 + r0) * DD, kh * 128, 4, acc);
            float* C = gh_p + (size_t)kh * (BB * G3);
            #pragma unroll
            for (int i = 0; i < 8; ++i) {
                int m = ty*8 + i;
                cstore(&C[(size_t)m * G3 + nt*32 + tx*2 + 0], acc[i][0]);
                cstore(&C[(size_t)m * G3 + nt*32 + tx*2 + 1], acc[i][1]);
            }
        }
        gbar(bar);
        // ---- GRU update (all cross-block data agent-scope) ----
        {
            int idx = bid * 256 + tid;
            if (idx < BB * DD) {
                int b = idx >> 10, d = idx & 1023;
                size_t o = (size_t)b * G3 + d;
                const float* gib = gi_buf + (size_t)(s & (CH-1)) * (BB * G3);
                float ir = cload(&gib[o]), iz = cload(&gib[o + DD]),
                      in_ = cload(&gib[o + 2*DD]);
                float hr = bhh[d], hz = bhh[DD + d], hn = bhh[2*DD + d];
                #pragma unroll
                for (int p = 0; p < 8; ++p) {
                    const float* g = gh_p + (size_t)p * (BB * G3);
                    hr += cload(&g[o]); hz += cload(&g[o + DD]); hn += cload(&g[o + 2*DD]);
                }
                float r = 1.0f / (1.0f + expf(-(ir + hr)));
                float z = 1.0f / (1.0f + expf(-(iz + hz)));
                float n = tanhf(in_ + r * hn);
                float hv = cload(&h[idx]);
                cstore(&h[idx], (1.0f - z) * n + z * hv);
            }
        }
        gbar(bar);
    }
}

__global__ __launch_bounds__(256, 3) void k_dec_p(
    const float* __restrict__ emb,
    const float* __restrict__ Wih, const float* __restrict__ bih,
    const float* __restrict__ Whh, const float* __restrict__ bhh,
    const float* __restrict__ outW, const float* __restrict__ outb,
    float* __restrict__ h, float* __restrict__ g_p,
    float* __restrict__ lg_p, int* __restrict__ tok,
    float* __restrict__ out, int KSL, unsigned* bar)
{
    __shared__ float As[32][132];
    __shared__ float Bs[32][34];
    float* sv = &As[0][0];            // overlap: argmax phase never uses As/Bs
    int*   si = (int*)&As[8][0];
    const int bid = blockIdx.x, tid = threadIdx.x;
    const int r0 = tid >> 3, tx = tid & 15, ty = tid >> 4;

    for (int t = 0; t < S_TGT; ++t) {
        // ---- gates: side=bid/384, kh=(bid%384)/96, nt=bid%96 (KS=4) ----
        {
            const int side = bid / 384;
            const int rem  = bid - side * 384;
            const int kh   = rem / 96, nt = rem % 96;
            float acc[8][2] = {};
            if (side) {
                const float* A0 = h + (size_t)(r0 +  0) * DD;
                const float* A1 = h + (size_t)(r0 + 32) * DD;
                const float* A2 = h + (size_t)(r0 + 64) * DD;
                const float* A3 = h + (size_t)(r0 + 96) * DD;
                gemm_core<true>(As, Bs, A0, A1, A2, A3,
                                Whh + (size_t)(nt*32 + r0) * DD, kh * 256, 8, acc);
            } else {
                const float* A0 = emb + (size_t)cloadi(&tok[r0 +  0]) * DD;
                const float* A1 = emb + (size_t)cloadi(&tok[r0 + 32]) * DD;
                const float* A2 = emb + (size_t)cloadi(&tok[r0 + 64]) * DD;
                const float* A3 = emb + (size_t)cloadi(&tok[r0 + 96]) * DD;
                gemm_core<false>(As, Bs, A0, A1, A2, A3,
                                 Wih + (size_t)(nt*32 + r0) * DD, kh * 256, 8, acc);
            }
            float* C = g_p + (size_t)(side*4 + kh) * (BB * G3);
            #pragma unroll
            for (int i = 0; i < 8; ++i) {
                int m = ty*8 + i;
                cstore(&C[(size_t)m * G3 + nt*32 + tx*2 + 0], acc[i][0]);
                cstore(&C[(size_t)m * G3 + nt*32 + tx*2 + 1], acc[i][1]);
            }
        }
        gbar(bar);
        // ---- GRU update: gi = slots 0..3 + bih, gh = slots 4..7 + bhh ----
        {
            int idx = bid * 256 + tid;
            if (idx < BB * DD) {
                int b = idx >> 10, d = idx & 1023;
                size_t o = (size_t)b * G3 + d;
                float ir = bih[d], iz = bih[DD + d], in_ = bih[2*DD + d];
                #pragma unroll
                for (int p = 0; p < 4; ++p) {
                    const float* g = g_p + (size_t)p * (BB * G3);
                    ir += cload(&g[o]); iz += cload(&g[o + DD]); in_ += cload(&g[o + 2*DD]);
                }
                float hr = bhh[d], hz = bhh[DD + d], hn = bhh[2*DD + d];
                #pragma unroll
                for (int p = 4; p < 8; ++p) {
                    const float* g = g_p + (size_t)p * (BB * G3);
                    hr += cload(&g[o]); hz += cload(&g[o + DD]); hn += cload(&g[o + 2*DD]);
                }
                float r = 1.0f / (1.0f + expf(-(ir + hr)));
                float z = 1.0f / (1.0f + expf(-(iz + hz)));
                float n = tanhf(in_ + r * hn);
                float hv = cload(&h[idx]);
                cstore(&h[idx], (1.0f - z) * n + z * hv);
            }
        }
        gbar(bar);
        // ---- logits: kh=bid/250 (<KSL active), nt=bid%250, coh A ----
        {
            const int kh = bid / 250, nt = bid % 250;
            if (kh < KSL) {                      // block-uniform
                const int t0 = (32 * kh) / KSL, t1 = (32 * (kh + 1)) / KSL;
                const float* A0 = h + (size_t)(r0 +  0) * DD;
                const float* A1 = h + (size_t)(r0 + 32) * DD;
                const float* A2 = h + (size_t)(r0 + 64) * DD;
                const float* A3 = h + (size_t)(r0 + 96) * DD;
                float acc[8][2] = {};
                gemm_core<true>(As, Bs, A0, A1, A2, A3,
                                outW + (size_t)(nt*32 + r0) * DD, t0 * 32, t1 - t0, acc);
                float* C = lg_p + (size_t)kh * (BB * VOUT);
                #pragma unroll
                for (int i = 0; i < 8; ++i) {
                    int m = ty*8 + i;
                    cstore(&C[(size_t)m * VOUT + nt*32 + tx*2 + 0], acc[i][0]);
                    cstore(&C[(size_t)m * VOUT + nt*32 + tx*2 + 1], acc[i][1]);
                }
            }
        }
        gbar(bar);
        // ---- fused: sum partials + bias -> out row (cached store, host-only
        //      reader), argmax -> tok (agent store) ----
        if (bid < BB) {                          // block-uniform
            const int b = bid;
            const size_t ro = (size_t)b * VOUT;
            float* Ct = out + (size_t)t * (BB * VOUT) + ro;
            float bv = -INFINITY; int bi = 0x7fffffff;
            for (int v = tid * 4; v < VOUT; v += 1024) {
                float4 rr = *reinterpret_cast<const float4*>(outb + v);
                for (int kh = 0; kh < KSL; ++kh) {
                    const float* P = lg_p + (size_t)kh * (BB * VOUT) + ro + v;
                    rr.x += cload(P + 0); rr.y += cload(P + 1);
                    rr.z += cload(P + 2); rr.w += cload(P + 3);
                }
                *reinterpret_cast<float4*>(Ct + v) = rr;
                if (rr.x > bv) { bv = rr.x; bi = v + 0; }
                if (rr.y > bv) { bv = rr.y; bi = v + 1; }
                if (rr.z > bv) { bv = rr.z; bi = v + 2; }
                if (rr.w > bv) { bv = rr.w; bi = v + 3; }
            }
            sv[tid] = bv; si[tid] = bi;
            __syncthreads();
            for (int st = 128; st > 0; st >>= 1) {
                if (tid < st) {
                    if (sv[tid+st] > sv[tid] ||
                        (sv[tid+st] == sv[tid] && si[tid+st] < si[tid])) {
                        sv[tid] = sv[tid+st]; si[tid] = si[tid+st];
                    }
                }
                __syncthreads();
            }
            if (tid == 0) cstorei(&tok[b], si[0]);
        }
        gbar(bar);
    }
}

// ===========================================================================
// FALLBACK PATH (round-1 proven multi-launch kernels, plain cached accesses)
// ===========================================================================

__global__ __launch_bounds__(256) void k_gi_chunk(
    const float* __restrict__ emb, const int* __restrict__ src_c,
    const float* __restrict__ Wih, const float* __restrict__ bih,
    float* __restrict__ gi_buf)
{
    __shared__ float As[32][132];
    __shared__ float Bs[32][34];
    const int n0    = blockIdx.x * 32;
    const int mbase = blockIdx.y * 128;
    const int tid = threadIdx.x;
    const int r0  = tid >> 3, tx = tid & 15, ty = tid >> 4;

    const float* A[4];
    #pragma unroll
    for (int p = 0; p < 4; ++p)
        A[p] = emb + (size_t)src_c[mbase + r0 + p * 32] * DD;
    float acc[8][2] = {};
    gemm_core<false>(As, Bs, A[0], A[1], A[2], A[3],
                     Wih + (size_t)(n0 + r0) * DD, 0, DD/32, acc);
    #pragma unroll
    for (int i = 0; i < 8; ++i) {
        size_t m = (size_t)(mbase + ty*8 + i);
        #pragma unroll
        for (int j = 0; j < 2; ++j) {
            int n = n0 + tx*2 + j;
            gi_buf[m * G3 + n] = acc[i][j] + bih[n];
        }
    }
}

__global__ __launch_bounds__(256) void k_gates_ks(
    const float* __restrict__ emb, const int* __restrict__ tok,
    const float* __restrict__ h,
    const float* __restrict__ Wih, const float* __restrict__ Whh,
    float* __restrict__ gi_base, float* __restrict__ gh_base,
    int side_base)
{
    __shared__ float As[32][132];
    __shared__ float Bs[32][34];
    const int side = side_base + blockIdx.y;
    const int kh   = blockIdx.z;
    const int kseg = DD / KS_F;
    const float* __restrict__ W = side ? Whh : Wih;
    float* __restrict__ C = (side ? gh_base : gi_base) + (size_t)kh * (BB * G3);

    const int n0  = blockIdx.x * 32;
    const int tid = threadIdx.x;
    const int r0  = tid >> 3, tx = tid & 15, ty = tid >> 4;

    const float* A[4];
    #pragma unroll
    for (int p = 0; p < 4; ++p) {
        int m = r0 + p * 32;
        A[p] = side ? (h + (size_t)m * DD) : (emb + (size_t)tok[m] * DD);
    }
    float acc[8][2] = {};
    gemm_core<false>(As, Bs, A[0], A[1], A[2], A[3],
                     W + (size_t)(n0 + r0) * DD, kh * kseg, kseg / 32, acc);
    #pragma unroll
    for (int i = 0; i < 8; ++i) {
        size_t m = (size_t)(ty*8 + i);
        C[m * G3 + n0 + tx*2 + 0] = acc[i][0];
        C[m * G3 + n0 + tx*2 + 1] = acc[i][1];
    }
}

__global__ __launch_bounds__(256) void k_logits_ks(
    const float* __restrict__ h, const float* __restrict__ W,
    float* __restrict__ p_base)
{
    __shared__ float As[32][132];
    __shared__ float Bs[32][34];
    const int kh   = blockIdx.y;          // KSL fixed = 2
    const int kseg = DD / 2;
    float* __restrict__ C = p_base + (size_t)kh * (BB * VOUT);

    const int n0  = blockIdx.x * 32;
    const int tid = threadIdx.x;
    const int r0  = tid >> 3, tx = tid & 15, ty = tid >> 4;

    const float* A[4];
    #pragma unroll
    for (int p = 0; p < 4; ++p) A[p] = h + (size_t)(r0 + p * 32) * DD;
    float acc[8][2] = {};
    gemm_core<false>(As, Bs, A[0], A[1], A[2], A[3],
                     W + (size_t)(n0 + r0) * DD, kh * kseg, kseg / 32, acc);
    #pragma unroll
    for (int i = 0; i < 8; ++i) {
        size_t m = (size_t)(ty*8 + i);
        C[m * VOUT + n0 + tx*2 + 0] = acc[i][0];
        C[m * VOUT + n0 + tx*2 + 1] = acc[i][1];
    }
}

__global__ __launch_bounds__(256) void k_update_f(
    const float* __restrict__ gi_base, int ns_i, const float* __restrict__ bih,
    const float* __restrict__ gh_base, int ns_h, const float* __restrict__ bhh,
    float* __restrict__ h)
{
    int idx = blockIdx.x * 256 + threadIdx.x;
    int b = idx >> 10, d = idx & 1023;
    size_t o = (size_t)b * G3 + d;

    float ir = 0.f, iz = 0.f, in_ = 0.f;
    for (int p = 0; p < ns_i; ++p) {
        const float* g = gi_base + (size_t)p * (BB * G3);
        ir += g[o]; iz += g[o + DD]; in_ += g[o + 2*DD];
    }
    if (bih) { ir += bih[d]; iz += bih[DD + d]; in_ += bih[2*DD + d]; }

    float hr = 0.f, hz = 0.f, hn = 0.f;
    for (int p = 0; p < ns_h; ++p) {
        const float* g = gh_base + (size_t)p * (BB * G3);
        hr += g[o]; hz += g[o + DD]; hn += g[o + 2*DD];
    }
    hr += bhh[d]; hz += bhh[DD + d]; hn += bhh[2*DD + d];

    float r = 1.0f / (1.0f + expf(-(ir + hr)));
    float z = 1.0f / (1.0f + expf(-(iz + hz)));
    float n = tanhf(in_ + r * hn);
    float hv = h[idx];
    h[idx] = (1.0f - z) * n + z * hv;
}

__global__ __launch_bounds__(256) void k_argmax_out(
    const float* __restrict__ p0, const float* __restrict__ p1,
    const float* __restrict__ bias,
    float* __restrict__ outC, int* __restrict__ tok)
{
    const int b = blockIdx.x;
    const size_t ro = (size_t)b * VOUT;
    const int tid = threadIdx.x;

    float bv = -INFINITY; int bi = 0x7fffffff;
    for (int v = tid * 4; v < VOUT; v += 1024) {
        float4 a = *reinterpret_cast<const float4*>(p0 + ro + v);
        float4 c = *reinterpret_cast<const float4*>(p1 + ro + v);
        float4 bb = *reinterpret_cast<const float4*>(bias + v);
        float4 r;
        r.x = a.x + c.x + bb.x;
        r.y = a.y + c.y + bb.y;
        r.z = a.z + c.z + bb.z;
        r.w = a.w + c.w + bb.w;
        *reinterpret_cast<float4*>(outC + ro + v) = r;
        if (r.x > bv) { bv = r.x; bi = v + 0; }
        if (r.y > bv) { bv = r.y; bi = v + 1; }
        if (r.z > bv) { bv = r.z; bi = v + 2; }
        if (r.w > bv) { bv = r.w; bi = v + 3; }
    }
    __shared__ float sv[256];
    __shared__ int   si[256];
    sv[tid] = bv; si[tid] = bi;
    __syncthreads();
    for (int s = 128; s > 0; s >>= 1) {
        if (tid < s) {
            if (sv[tid+s] > sv[tid] || (sv[tid+s] == sv[tid] && si[tid+s] < si[tid])) {
                sv[tid] = sv[tid+s]; si[tid] = si[tid+s];
            }
        }
        __syncthreads();
    }
    if (tid == 0) tok[b] = si[0];
}

// ---------------------------------------------------------------------------
extern "C" void kernel_launch(void* const* d_in, const int* in_sizes, int n_in,
                              void* d_out, int out_size, void* d_ws, size_t ws_size,
                              hipStream_t stream) {
    const int*   src     = (const int*)  d_in[0];
    const float* enc_emb = (const float*)d_in[2];
    const float* eWih    = (const float*)d_in[3];
    const float* eWhh    = (const float*)d_in[4];
    const float* ebih    = (const float*)d_in[5];
    const float* ebhh    = (const float*)d_in[6];
    const float* dec_emb = (const float*)d_in[7];
    const float* dWih    = (const float*)d_in[8];
    const float* dWhh    = (const float*)d_in[9];
    const float* dbih    = (const float*)d_in[10];
    const float* dbhh    = (const float*)d_in[11];
    const float* outW    = (const float*)d_in[12];
    const float* outb    = (const float*)d_in[13];
    float* out = (float*)d_out;

    // workspace layout (bar strictly AFTER tok[0..127])
    float* h    = (float*)d_ws;                 // 128*1024
    float* g_p  = h + BB * DD;                  // 8 * 128*3072 (gate partials)
    int*  tok   = (int*)(g_p + 8 * BB * G3);    // tok[0..127]
    unsigned* bar = (unsigned*)(tok + 128);     // own 128B line
    float* scratch = (float*)(tok + 256);       // enc gi chunks / logits partials

    size_t fixed = (size_t)((char*)scratch - (char*)d_ws);
    size_t avail = (ws_size > fixed) ? ws_size - fixed : 0;
    int KSLv = (avail >= (size_t)3 * BB * VOUT * 4) ? 3 : 2;
    int CH = 8;
    while (CH > 1 && (size_t)CH * BB * G3 * 4 > avail) CH >>= 1;

    float* gi_buf = scratch;                    // encoder phase
    float* lg_p   = scratch;                    // decoder phase

    // certify persistent-path co-residency (host-only queries, capture-safe)
    static int persist_ok = -1;
    if (persist_ok < 0) {
        int nb_e = 0, nb_d = 0, ncu = 0, dev = 0;
        hipError_t e0 = hipGetDevice(&dev);
        hipError_t e1 = hipOccupancyMaxActiveBlocksPerMultiprocessor(
            &nb_e, (const void*)k_enc_p, 256, 0);
        hipError_t e2 = hipOccupancyMaxActiveBlocksPerMultiprocessor(
            &nb_d, (const void*)k_dec_p, 256, 0);
        hipError_t e3 = hipDeviceGetAttribute(
            &ncu, hipDeviceAttributeMultiprocessorCount, dev);
        persist_ok = (e0 == hipSuccess && e1 == hipSuccess && e2 == hipSuccess &&
                      e3 == hipSuccess && nb_e >= 3 && nb_d >= 3 &&
                      (long)ncu * 3 >= GRID) ? 1 : 0;
    }

    k_init<<<512, 256, 0, stream>>>(h, tok, bar);

    if (persist_ok == 1) {
        k_enc_p<<<GRID, 256, 0, stream>>>(enc_emb, src, eWih, ebih, eWhh, ebhh,
                                          h, g_p, gi_buf, CH, bar);
        k_dec_p<<<GRID, 256, 0, stream>>>(dec_emb, dWih, dbih, dWhh, dbhh,
                                          outW, outb, h, g_p, lg_p, tok,
                                          out, KSLv, bar);
    } else {
        // ---- round-1 proven multi-launch path ----
        float* gi_p = g_p;                      // slots 0..3
        float* gh_p = g_p + 4 * BB * G3;        // slots 4..7
        float* p0   = scratch;
        float* p1   = scratch + BB * VOUT;

        for (int c = 0; c < S_SRC; c += CH) {
            k_gi_chunk<<<dim3(96, CH), 256, 0, stream>>>(enc_emb, src + c * BB,
                                                         eWih, ebih, gi_buf);
            for (int s = 0; s < CH; ++s) {
                k_gates_ks<<<dim3(96, 1, KS_F), 256, 0, stream>>>(
                    enc_emb, tok, h, eWih, eWhh, nullptr, gh_p, 1);
                k_update_f<<<512, 256, 0, stream>>>(
                    gi_buf + (size_t)s * BB * G3, 1, nullptr, gh_p, KS_F, ebhh, h);
            }
        }
        for (int t = 0; t < S_TGT; ++t) {
            k_gates_ks<<<dim3(96, 2, KS_F), 256, 0, stream>>>(
                dec_emb, tok, h, dWih, dWhh, gi_p, gh_p, 0);
            k_update_f<<<512, 256, 0, stream>>>(gi_p, KS_F, dbih, gh_p, KS_F, dbhh, h);
            k_logits_ks<<<dim3(250, 2), 256, 0, stream>>>(h, outW, p0);
            float* Ct = out + (size_t)t * BB * VOUT;
            k_argmax_out<<<128, 256, 0, stream>>>(p0, p1, outb, Ct, tok);
        }
    }
}